// Round 5
// baseline (60978.949 us; speedup 1.0000x reference)
//
#include <hip/hip_runtime.h>
#include <hip/hip_bf16.h>
#include <stdint.h>

#define T_SEQ 8192
#define E_IN  512
#define H_DIM 1024
#define FH    4096   // 4*H
#define H2    2048   // 2*H
#define NLAB  5
#define NEGV  (-10000.0f)

typedef __attribute__((ext_vector_type(8))) short bf16x8;
typedef __attribute__((ext_vector_type(4))) float f32x4;

__device__ __forceinline__ uint32_t f2bf(float f) {
  uint32_t x = __float_as_uint(f);
  return (x + 0x7FFFu + ((x >> 16) & 1u)) >> 16;   // RNE f32->bf16
}
__device__ __forceinline__ uint32_t pack2bf(float lo, float hi) {
  return f2bf(lo) | (f2bf(hi) << 16);
}
__device__ __forceinline__ float bf2f(uint32_t b) {
  return __uint_as_float(b << 16);
}
__device__ __forceinline__ float fsig(float x) { return 1.0f / (1.0f + __expf(-x)); }
__device__ __forceinline__ float ftanh(float x) {
  float ax = fabsf(x);
  float e = __expf(-2.0f * ax);
  float t = (1.0f - e) / (1.0f + e);
  return copysignf(t, x);
}

// ---------------------------------------------------------------- bias prep
__global__ void bias_kernel(const float* bi0, const float* bh0,
                            const float* bi0r, const float* bh0r,
                            const float* bi1, const float* bh1,
                            const float* bi1r, const float* bh1r,
                            float* bsum) {
  int i = blockIdx.x * blockDim.x + threadIdx.x;  // 0..16383
  int d = i >> 12, j = i & 4095;
  const float *a, *b;
  switch (d) {
    case 0:  a = bi0;  b = bh0;  break;
    case 1:  a = bi0r; b = bh0r; break;
    case 2:  a = bi1;  b = bh1;  break;
    default: a = bi1r; b = bh1r; break;
  }
  bsum[i] = a[j] + b[j];
}

// ---------------------------------------------------------------- xg GEMM
// C[8192][4096](bf16) = A[8192][K] x Bt[4096][K]^T + bias[4096], written in
// PERMUTED column order: pcol = ((col&1023)>>4)*64 + (col>>10)*16 + (col&15),
// so LSTM WG g reads its 64 gate values as one contiguous 128 B line.
template <bool AF32>
__global__ __launch_bounds__(256) void gemm_xg(const void* Aptr, const float* Bt,
                                               const float* bias, uint16_t* C, int K) {
  const int m0 = blockIdx.x * 128;
  const int n0 = blockIdx.y * 128;
  __shared__ uint32_t As[128 * 20];  // 128 x 40 bf16 (32 + 8 pad)
  __shared__ uint32_t Bs[128 * 20];
  const int tid  = threadIdx.x;
  const int lane = tid & 63;
  const int wave = tid >> 6;
  const int wr = wave >> 1, wc = wave & 1;
  const int row = tid >> 1;   // 0..127
  const int seg = tid & 1;    // 16-element segment

  f32x4 acc[4][4];
#pragma unroll
  for (int i = 0; i < 4; ++i)
#pragma unroll
    for (int j = 0; j < 4; ++j)
      acc[i][j] = (f32x4){0.0f, 0.0f, 0.0f, 0.0f};

  const int nk = K / 32;
  for (int kk = 0; kk < nk; ++kk) {
    const int k0 = kk * 32;
    uint32_t* dst = &As[row * 20 + seg * 8];
    if (AF32) {
      const float4* src = (const float4*)((const float*)Aptr + (size_t)(m0 + row) * K + k0 + seg * 16);
      uint32_t w[8];
#pragma unroll
      for (int u = 0; u < 4; ++u) {
        float4 v = src[u];
        w[2 * u]     = pack2bf(v.x, v.y);
        w[2 * u + 1] = pack2bf(v.z, v.w);
      }
      ((uint4*)dst)[0] = make_uint4(w[0], w[1], w[2], w[3]);
      ((uint4*)dst)[1] = make_uint4(w[4], w[5], w[6], w[7]);
    } else {
      const uint4* src = (const uint4*)((const uint16_t*)Aptr + (size_t)(m0 + row) * K + k0 + seg * 16);
      ((uint4*)dst)[0] = src[0];
      ((uint4*)dst)[1] = src[1];
    }
    {
      const float4* src = (const float4*)(Bt + (size_t)(n0 + row) * K + k0 + seg * 16);
      uint32_t w[8];
#pragma unroll
      for (int u = 0; u < 4; ++u) {
        float4 v = src[u];
        w[2 * u]     = pack2bf(v.x, v.y);
        w[2 * u + 1] = pack2bf(v.z, v.w);
      }
      uint32_t* dstb = &Bs[row * 20 + seg * 8];
      ((uint4*)dstb)[0] = make_uint4(w[0], w[1], w[2], w[3]);
      ((uint4*)dstb)[1] = make_uint4(w[4], w[5], w[6], w[7]);
    }
    __syncthreads();

    const int mfrag = lane & 15, kq = lane >> 4;
    bf16x8 af[4], bfr[4];
#pragma unroll
    for (int i = 0; i < 4; ++i) {
      af[i]  = *(const bf16x8*)&As[(wr * 64 + i * 16 + mfrag) * 20 + kq * 4];
      bfr[i] = *(const bf16x8*)&Bs[(wc * 64 + i * 16 + mfrag) * 20 + kq * 4];
    }
#pragma unroll
    for (int i = 0; i < 4; ++i)
#pragma unroll
      for (int j = 0; j < 4; ++j)
        acc[i][j] = __builtin_amdgcn_mfma_f32_16x16x32_bf16(af[i], bfr[j], acc[i][j], 0, 0, 0);
    __syncthreads();
  }

  // epilogue: C/D layout col=lane&15 (B/n index), row=(lane>>4)*4+reg (A/m index)
  const int colq = lane & 15, rowq = lane >> 4;
#pragma unroll
  for (int j = 0; j < 4; ++j) {
    const int col = n0 + wc * 64 + j * 16 + colq;
    const float bv = bias[col];
    const int pcol = ((col & 1023) >> 4) * 64 + (col >> 10) * 16 + (col & 15);
#pragma unroll
    for (int i = 0; i < 4; ++i) {
#pragma unroll
      for (int r = 0; r < 4; ++r) {
        const int rrow = m0 + wr * 64 + i * 16 + rowq * 4 + r;
        C[(size_t)rrow * FH + pcol] = (uint16_t)f2bf(acc[i][j][r] + bv);
      }
    }
  }
}

// ---------------------------------------------------------------- LSTM layer
// 128 persistent WGs x 512 thr: dir = bid&1, g = bid>>1 owns h[16g..16g+16).
// WAVE-OWNS-ROWS: wave w of a WG owns h-indices j0=16g+2w, j0+1 end-to-end:
// it holds the 8 W_hh rows (4 gates x 2 idx) striped stride-64 across lanes
// (128 f32/thread), computes the full 1024-dot with a 5-level butterfly +
// one cross-half combine, applies activations in-lane, and publishes its
// 2 h-words as a single b64 atomic store. ONE barrier per step (h broadcast).
// Exchange: self-tagged words ((s<<16)|bf16), parity double-buffered, relaxed
// agent atomics, 2-deep pipelined poll (two outstanding loads -> sampling
// period ~ latency/2, shrinking the max-over-WGs straggler tail).
// Safety: a wave can overwrite h_lds/xg_lds for step s+1 only after its poll
// observed ALL step-s tags; every wave publishes step s only after its last
// LDS read of step s. Parity double-buffer makes one-step lag safe. 0xAA
// poison -> tag 0xAAAA never matches (s < 8192): no init needed.
__global__ __launch_bounds__(512, 2) void lstm_layer(
    const float* __restrict__ whh_f, const float* __restrict__ whh_b,
    const uint16_t* __restrict__ xg_f, const uint16_t* __restrict__ xg_b,
    uint32_t* hpub_f, uint32_t* hpub_b, uint16_t* __restrict__ hseq) {
  const int bid = blockIdx.x;
  const int dir = bid & 1;
  const int g   = bid >> 1;      // 0..63
  const int hb  = g * 16;
  const int tid = threadIdx.x;
  const int lane = tid & 63;
  const int wv   = tid >> 6;     // wave 0..7
  const int j0   = hb + 2 * wv;  // first h-index owned by this wave
  const int ph   = lane >> 5;    // pair select: lanes 0-31 -> j0, 32-63 -> j0+1

  const float*    whh  = dir ? whh_b : whh_f;
  const uint16_t* xg   = dir ? xg_b : xg_f;
  uint32_t*       hpub = dir ? hpub_b : hpub_f;
  const int colbase    = dir ? H_DIM : 0;

  __shared__ __align__(16) float h_lds[H_DIM];
  __shared__ __align__(8)  float xg_lds[64];

  // Wr[q*2+p][i] = W_hh[q*H + j0 + p][i*64 + lane]  (128 f32/thread)
  float Wr[8][16];
#pragma unroll
  for (int q = 0; q < 4; ++q)
#pragma unroll
    for (int p = 0; p < 2; ++p) {
      const float* row = whh + (size_t)(q * H_DIM + j0 + p) * H_DIM + lane;
#pragma unroll
      for (int i = 0; i < 16; ++i)
        Wr[q * 2 + p][i] = row[i * 64];
    }

  float cstate = 0.0f;  // lanes 0-31: c[j0] (redundant); lanes 32-63: c[j0+1]

  for (int s = 0; s < T_SEQ; ++s) {
    const int t = dir ? (T_SEQ - 1 - s) : s;

    // stage xg for this WG (64 contiguous bf16 = one line); barrier covers it
    if (tid < 64) xg_lds[tid] = bf2f(xg[(size_t)t * FH + g * 64 + tid]);

    if (s == 0) {
      ((float2*)h_lds)[tid] = make_float2(0.f, 0.f);
    } else {
      const uint32_t et = (uint32_t)(s - 1) << 16;
      const uint64_t etag = ((uint64_t)et << 32) | et;
      unsigned long long* hp =
          (unsigned long long*)(hpub + (((s - 1) & 1) ? H_DIM : 0)) + tid;
      // 2-deep pipelined spin: keep two loads outstanding
      unsigned long long a = __hip_atomic_load(hp, __ATOMIC_RELAXED, __HIP_MEMORY_SCOPE_AGENT);
      unsigned long long b = __hip_atomic_load(hp, __ATOMIC_RELAXED, __HIP_MEMORY_SCOPE_AGENT);
      unsigned long long v;
      for (;;) {
        if (((a ^ etag) & 0xFFFF0000FFFF0000ull) == 0) { v = a; break; }
        a = __hip_atomic_load(hp, __ATOMIC_RELAXED, __HIP_MEMORY_SCOPE_AGENT);
        if (((b ^ etag) & 0xFFFF0000FFFF0000ull) == 0) { v = b; break; }
        b = __hip_atomic_load(hp, __ATOMIC_RELAXED, __HIP_MEMORY_SCOPE_AGENT);
      }
      h_lds[2 * tid]     = bf2f((uint32_t)v & 0xFFFFu);
      h_lds[2 * tid + 1] = bf2f((uint32_t)(v >> 32) & 0xFFFFu);
    }
    __syncthreads();  // h_lds + xg_lds ready

    // full 1024-dot for this wave's 8 rows; lane l covers k = l + 64*i
    float acc[8] = {0.f, 0.f, 0.f, 0.f, 0.f, 0.f, 0.f, 0.f};
#pragma unroll
    for (int i = 0; i < 16; ++i) {
      float hv = h_lds[i * 64 + lane];   // stride-1 across lanes: conflict-free
#pragma unroll
      for (int vv = 0; vv < 8; ++vv) acc[vv] += Wr[vv][i] * hv;
    }
    // 5-level butterfly: sums within each 32-lane half
#pragma unroll
    for (int off = 1; off <= 16; off <<= 1)
#pragma unroll
      for (int vv = 0; vv < 8; ++vv) acc[vv] += __shfl_xor(acc[vv], off);
    // cross-half combine: half ph needs full sum of acc[q*2+ph]
    float gv[4];
#pragma unroll
    for (int q = 0; q < 4; ++q) {
      float mine = ph ? acc[q * 2 + 1] : acc[q * 2 + 0];
      float send = ph ? acc[q * 2 + 0] : acc[q * 2 + 1];
      gv[q] = mine + __shfl_xor(send, 32) + xg_lds[q * 16 + 2 * wv + ph];
    }

    float i_s = fsig(gv[0]), f_s = fsig(gv[1]), g_t = ftanh(gv[2]), o_s = fsig(gv[3]);
    cstate = f_s * cstate + i_s * g_t;
    float h = o_s * ftanh(cstate);
    uint32_t myw = ((uint32_t)s << 16) | f2bf(h);
    uint32_t otw = __shfl_xor(myw, 32);  // the other pair-member's word
    if (lane == 0) {
      unsigned long long pw = ((unsigned long long)otw << 32) | myw;
      __hip_atomic_store((unsigned long long*)(hpub + (s & 1) * H_DIM + j0), pw,
                         __ATOMIC_RELAXED, __HIP_MEMORY_SCOPE_AGENT);
      ((uint32_t*)hseq)[((size_t)t * H2 + colbase + j0) >> 1] =
          (myw & 0xFFFFu) | (otw << 16);
    }
    // no trailing barrier: next-step LDS overwrites are gated by the poll.
  }
}

// ---------------------------------------------------------------- feats
// feats[t][l] = h1[t,:] . w_out[l,:] + b_out[l];  one wave per row.
__global__ __launch_bounds__(256) void feats_kernel(const uint16_t* __restrict__ h1,
                                                    const float* __restrict__ wout,
                                                    const float* __restrict__ bout,
                                                    float* __restrict__ feats) {
  const int lane = threadIdx.x & 63;
  const int wid  = (blockIdx.x * blockDim.x + threadIdx.x) >> 6;
  const int nwaves = (gridDim.x * blockDim.x) >> 6;

  float wreg[5][32];
#pragma unroll
  for (int j = 0; j < 5; ++j) {
    const float4* src = (const float4*)(wout + j * H2 + lane * 32);
#pragma unroll
    for (int u = 0; u < 8; ++u) {
      float4 v = src[u];
      wreg[j][u * 4 + 0] = v.x; wreg[j][u * 4 + 1] = v.y;
      wreg[j][u * 4 + 2] = v.z; wreg[j][u * 4 + 3] = v.w;
    }
  }
  for (int t = wid; t < T_SEQ; t += nwaves) {
    const uint32_t* hrow = (const uint32_t*)(h1 + (size_t)t * H2) + lane * 16;
    float acc[5] = {0.f, 0.f, 0.f, 0.f, 0.f};
#pragma unroll
    for (int u = 0; u < 16; ++u) {
      uint32_t w2 = hrow[u];
      float hlo = __uint_as_float(w2 << 16);
      float hhi = __uint_as_float(w2 & 0xFFFF0000u);
#pragma unroll
      for (int j = 0; j < 5; ++j)
        acc[j] += wreg[j][u * 2] * hlo + wreg[j][u * 2 + 1] * hhi;
    }
#pragma unroll
    for (int off = 32; off >= 1; off >>= 1)
#pragma unroll
      for (int j = 0; j < 5; ++j)
        acc[j] += __shfl_xor(acc[j], off);
    if (lane < 5) feats[t * NLAB + lane] = acc[lane] + bout[lane];
  }
}

// ---------------------------------------------------------------- Viterbi
// Parallel max-plus scan (chunks of 32 per thread), bps in LDS, pointer-jump backtrack.
__global__ __launch_bounds__(256) void viterbi_kernel(const float* __restrict__ feats,
                                                      const float* __restrict__ trans,
                                                      float* __restrict__ out) {
  __shared__ float scanM[256][26];
  __shared__ uint16_t bpsL[T_SEQ];
  __shared__ int bestL;
  const int tid = threadIdx.x;

  float tr[5][5];
#pragma unroll
  for (int n = 0; n < 5; ++n)
#pragma unroll
    for (int p = 0; p < 5; ++p) tr[n][p] = trans[n * 5 + p];

  // phase 1: per-thread chunk composite
  float C[5][5];
  {
    const int t0 = tid * 32;
    const float* f = feats + (size_t)t0 * 5;
#pragma unroll
    for (int n = 0; n < 5; ++n)
#pragma unroll
      for (int p = 0; p < 5; ++p) C[n][p] = tr[n][p] + f[n];
    for (int t = 1; t < 32; ++t) {
      const float* ft = feats + (size_t)(t0 + t) * 5;
      float Nw[5][5];
#pragma unroll
      for (int n = 0; n < 5; ++n) {
#pragma unroll
        for (int p = 0; p < 5; ++p) {
          float m = tr[n][0] + C[0][p];
#pragma unroll
          for (int k = 1; k < 5; ++k) m = fmaxf(m, tr[n][k] + C[k][p]);
          Nw[n][p] = m + ft[n];
        }
      }
#pragma unroll
      for (int n = 0; n < 5; ++n)
#pragma unroll
        for (int p = 0; p < 5; ++p) C[n][p] = Nw[n][p];
    }
#pragma unroll
    for (int n = 0; n < 5; ++n)
#pragma unroll
      for (int p = 0; p < 5; ++p) scanM[tid][n * 5 + p] = C[n][p];
  }
  __syncthreads();

  // phase 2: Hillis-Steele inclusive scan
  for (int d = 1; d < 256; d <<= 1) {
    float A[5][5], B[5][5];
    const bool has = (tid >= d);
#pragma unroll
    for (int n = 0; n < 5; ++n)
#pragma unroll
      for (int p = 0; p < 5; ++p) A[n][p] = scanM[tid][n * 5 + p];
    if (has) {
#pragma unroll
      for (int n = 0; n < 5; ++n)
#pragma unroll
        for (int p = 0; p < 5; ++p) B[n][p] = scanM[tid - d][n * 5 + p];
    }
    __syncthreads();
    if (has) {
#pragma unroll
      for (int n = 0; n < 5; ++n) {
#pragma unroll
        for (int p = 0; p < 5; ++p) {
          float m = A[n][0] + B[0][p];
#pragma unroll
          for (int k = 1; k < 5; ++k) m = fmaxf(m, A[n][k] + B[k][p]);
          scanM[tid][n * 5 + p] = m;
        }
      }
    }
    __syncthreads();
  }

  // base vector for this chunk
  float fv[5];
  if (tid == 0) {
#pragma unroll
    for (int n = 0; n < 5; ++n) fv[n] = (n == 3) ? 0.0f : NEGV;
  } else {
#pragma unroll
    for (int n = 0; n < 5; ++n) {
      float m = scanM[tid - 1][n * 5 + 3];
#pragma unroll
      for (int p = 0; p < 5; ++p)
        if (p != 3) m = fmaxf(m, scanM[tid - 1][n * 5 + p] + NEGV);
      fv[n] = m;
    }
  }

  // phase 3: exact sequential within chunk; emit backpointers
  {
    const int t0 = tid * 32;
    for (int t = 0; t < 32; ++t) {
      const float* ft = feats + (size_t)(t0 + t) * 5;
      float nf[5];
      uint32_t bits = 0;
#pragma unroll
      for (int n = 0; n < 5; ++n) {
        float m = tr[n][0] + fv[0];
        int arg = 0;
#pragma unroll
        for (int p = 1; p < 5; ++p) {
          float s2 = tr[n][p] + fv[p];
          if (s2 > m) { m = s2; arg = p; }
        }
        nf[n] = m + ft[n];
        bits |= (uint32_t)arg << (3 * n);
      }
      bpsL[t0 + t] = (uint16_t)bits;
#pragma unroll
      for (int n = 0; n < 5; ++n) fv[n] = nf[n];
    }
    if (tid == 255) {
      float m = fv[0] + tr[4][0];
      int arg = 0;
#pragma unroll
      for (int p = 1; p < 5; ++p) {
        float s2 = fv[p] + tr[4][p];
        if (s2 > m) { m = s2; arg = p; }
      }
      out[0] = m;       // score
      bestL = arg;
    }
  }
  __syncthreads();

  // phase 4: pointer-jump suffix composition
  for (int d = 1; d < T_SEQ; d <<= 1) {
    uint32_t own[32], par[32];
#pragma unroll
    for (int k = 0; k < 32; ++k) {
      int t = tid + k * 256;
      own[k] = bpsL[t];
      par[k] = (t + d < T_SEQ) ? (uint32_t)bpsL[t + d] : 0u;
    }
    __syncthreads();
#pragma unroll
    for (int k = 0; k < 32; ++k) {
      int t = tid + k * 256;
      if (t + d < T_SEQ) {
        uint32_t fmp = own[k], gmp = par[k], r = 0;
#pragma unroll
        for (int x = 0; x < 5; ++x) {
          uint32_t j = (gmp >> (3 * x)) & 7u;
          uint32_t v = (fmp >> (3 * j)) & 7u;
          r |= v << (3 * x);
        }
        bpsL[t] = (uint16_t)r;
      }
    }
    __syncthreads();
  }

  const int best = bestL;
  for (int k = 0; k < 32; ++k) {
    int t = tid + k * 256;
    int lbl = (t == T_SEQ - 1) ? best : (int)((bpsL[t + 1] >> (3 * best)) & 7u);
    out[1 + t] = (float)lbl;
  }
}

// ---------------------------------------------------------------- launcher
extern "C" void kernel_launch(void* const* d_in, const int* in_sizes, int n_in,
                              void* d_out, int out_size, void* d_ws, size_t ws_size,
                              hipStream_t stream) {
  const float* hours     = (const float*)d_in[0];
  const float* w_ih_l0   = (const float*)d_in[1];
  const float* w_hh_l0   = (const float*)d_in[2];
  const float* b_ih_l0   = (const float*)d_in[3];
  const float* b_hh_l0   = (const float*)d_in[4];
  const float* w_ih_l0r  = (const float*)d_in[5];
  const float* w_hh_l0r  = (const float*)d_in[6];
  const float* b_ih_l0r  = (const float*)d_in[7];
  const float* b_hh_l0r  = (const float*)d_in[8];
  const float* w_ih_l1   = (const float*)d_in[9];
  const float* w_hh_l1   = (const float*)d_in[10];
  const float* b_ih_l1   = (const float*)d_in[11];
  const float* b_hh_l1   = (const float*)d_in[12];
  const float* w_ih_l1r  = (const float*)d_in[13];
  const float* w_hh_l1r  = (const float*)d_in[14];
  const float* b_ih_l1r  = (const float*)d_in[15];
  const float* b_hh_l1r  = (const float*)d_in[16];
  const float* w_out     = (const float*)d_in[17];
  const float* b_out     = (const float*)d_in[18];
  const float* transitions = (const float*)d_in[19];
  float* out = (float*)d_out;

  // ws layout (peak ~160.6 MB): h1seq aliases h0seq (h0 is dead once the
  // layer-1 gemms have consumed it; layer-1 lstm reads only xgf/xgb).
  char* ws = (char*)d_ws;
  size_t off = 0;
  auto alloc = [&](size_t bytes) -> void* {
    void* p = ws + off;
    off += (bytes + 255) & ~(size_t)255;
    return p;
  };
  uint16_t* xgf   = (uint16_t*)alloc((size_t)T_SEQ * FH * 2);   // 64 MB (reused for layer 1)
  uint16_t* xgb   = (uint16_t*)alloc((size_t)T_SEQ * FH * 2);   // 64 MB
  uint16_t* h0seq = (uint16_t*)alloc((size_t)T_SEQ * H2 * 2);   // 32 MB (h1seq aliases)
  uint16_t* h1seq = h0seq;
  float*    bsum  = (float*)alloc((size_t)4 * FH * 4);
  uint32_t* hpub  = (uint32_t*)alloc((size_t)2 * 2 * 2 * H_DIM * 4); // layer x dir x parity
  float*    feats = (float*)alloc((size_t)T_SEQ * NLAB * 4);
  (void)ws_size; (void)in_sizes; (void)n_in; (void)out_size;

  bias_kernel<<<64, 256, 0, stream>>>(b_ih_l0, b_hh_l0, b_ih_l0r, b_hh_l0r,
                                      b_ih_l1, b_hh_l1, b_ih_l1r, b_hh_l1r, bsum);
  dim3 gg(64, 32);
  gemm_xg<true><<<gg, 256, 0, stream>>>(hours, w_ih_l0,  bsum + 0 * FH, xgf, E_IN);
  gemm_xg<true><<<gg, 256, 0, stream>>>(hours, w_ih_l0r, bsum + 1 * FH, xgb, E_IN);
  lstm_layer<<<128, 512, 0, stream>>>(w_hh_l0, w_hh_l0r, xgf, xgb,
                                      hpub + 0, hpub + 2048, h0seq);
  gemm_xg<false><<<gg, 256, 0, stream>>>(h0seq, w_ih_l1,  bsum + 2 * FH, xgf, H2);
  gemm_xg<false><<<gg, 256, 0, stream>>>(h0seq, w_ih_l1r, bsum + 3 * FH, xgb, H2);
  lstm_layer<<<128, 512, 0, stream>>>(w_hh_l1, w_hh_l1r, xgf, xgb,
                                      hpub + 4096, hpub + 6144, h1seq);
  feats_kernel<<<128, 256, 0, stream>>>(h1seq, w_out, b_out, feats);
  viterbi_kernel<<<1, 256, 0, stream>>>(feats, transitions, out);
}